// Round 7
// baseline (8852.302 us; speedup 1.0000x reference)
//
#include <hip/hip_runtime.h>

// ---------------------------------------------------------------------------
// SubModel_22016002359901: 3x GCN(2 conv) + FC heads, N=100000, F=128, E=1.6M
// Round 7: round 6 + fix: zero_small must cover all NBUCK=391 cursors
// (was launched with 1 block of 256 -> buckets 256..390 had garbage cursors,
// dropping/corrupting edges for nodes >= 65536).
// ---------------------------------------------------------------------------

typedef short bf16x8 __attribute__((ext_vector_type(8)));
typedef float f32x4 __attribute__((ext_vector_type(4)));

#define BSHIFT 8                 // 256 dst nodes per bucket
#define NBUCK_MAX 400
#define BCAP 6144                // mean 4096 @ E=1.6M, sigma ~64 -> 32 sigma headroom

static __device__ __forceinline__ float frelu(float x) { return x > 0.f ? x : 0.f; }

static __device__ __forceinline__ unsigned short f2bf(float f) {
    unsigned int u = __float_as_uint(f);
    u += 0x7fffu + ((u >> 16) & 1u);           // RNE
    return (unsigned short)(u >> 16);
}
static __device__ __forceinline__ float bflo(unsigned int u) {
    return __uint_as_float(u << 16);
}
static __device__ __forceinline__ float bfhi(unsigned int u) {
    return __uint_as_float(u & 0xffff0000u);
}

// ---------------- conversion kernels ----------------
__global__ void xconv(const float* __restrict__ src, unsigned short* __restrict__ dst, int n4) {
    int i = blockIdx.x * 256 + threadIdx.x;
    if (i >= n4) return;
    float4 v = *(const float4*)(src + (size_t)i * 4);
    ushort4 o = {f2bf(v.x), f2bf(v.y), f2bf(v.z), f2bf(v.w)};
    *(ushort4*)(dst + (size_t)i * 4) = o;
}

__global__ void wtrans(const float* __restrict__ src, unsigned short* __restrict__ dst,
                       int K, int M) {
    int i = blockIdx.x * 256 + threadIdx.x;
    if (i >= K * M) return;
    int m = i / K, k = i % K;
    dst[i] = f2bf(src[(size_t)k * M + m]);
}

__global__ void zero_small(int* __restrict__ p, int n) {
    int i = blockIdx.x * 256 + threadIdx.x;
    if (i < n) p[i] = 0;
}

// ---------------- bucketed edge partition ----------------
// record = {src | dstlocal<<17, ew}; bucket = dst>>8
__global__ __launch_bounds__(256) void part_k(
    const int* __restrict__ src, const int* __restrict__ dst,
    const float* __restrict__ ew, int* __restrict__ gcur,
    int2* __restrict__ part, int nE, int nbuck) {
    __shared__ int lh[NBUCK_MAX];
    __shared__ int gb[NBUCK_MAX];
    const int tid = threadIdx.x;
    for (int t = tid; t < nbuck; t += 256) lh[t] = 0;
    __syncthreads();
    const int e0 = blockIdx.x * 4096;
    int rk[16], bk[16];
#pragma unroll
    for (int j = 0; j < 16; ++j) {
        int e = e0 + j * 256 + tid;
        rk[j] = -1;
        if (e < nE) {
            int b = dst[e] >> BSHIFT;
            bk[j] = b;
            rk[j] = atomicAdd(&lh[b], 1);
        }
    }
    __syncthreads();
    for (int t = tid; t < nbuck; t += 256)
        gb[t] = lh[t] ? atomicAdd(&gcur[t], lh[t]) : 0;
    __syncthreads();
#pragma unroll
    for (int j = 0; j < 16; ++j) {
        int e = e0 + j * 256 + tid;
        if (e >= nE) continue;
        int b = bk[j];
        int slot = gb[b] + rk[j];
        if (slot >= 0 && slot < BCAP) {
            int s = src[e];
            int dl = dst[e] & ((1 << BSHIFT) - 1);
            part[(size_t)b * BCAP + slot] = make_int2(s | (dl << 17), __float_as_int(ew[e]));
        }
    }
}

// per bucket: LDS f32 weighted-degree accumulation -> dinv
__global__ __launch_bounds__(256) void deg_bucket(
    const int2* __restrict__ part, const int* __restrict__ gcur,
    float* __restrict__ dinv, int n) {
    __shared__ float wd[256];
    const int b = blockIdx.x;
    const int t = threadIdx.x;
    wd[t] = 0.f;
    __syncthreads();
    int cnt = gcur[b];
    if (cnt > BCAP) cnt = BCAP;
    const int2* pb = part + (size_t)b * BCAP;
    for (int i = t; i < cnt; i += 256) {
        int2 p = pb[i];
        atomicAdd(&wd[(p.x >> 17) & 255], __int_as_float(p.y));
    }
    __syncthreads();
    int g = (b << BSHIFT) + t;
    if (g < n) dinv[g] = rsqrtf(1.f + wd[t]);
}

// one block per bucket: 256x128 f32 accumulator in LDS.
// aggr[g] = relu( dinv[g] * sum_e(dinv[src]*ew*h[src]) + dinv[g]^2*h[g] + bias )
__global__ __launch_bounds__(1024) void agg_bucket(
    const int2* __restrict__ part, const int* __restrict__ gcur,
    const unsigned short* __restrict__ h, const float* __restrict__ dinv,
    const float* __restrict__ bias, unsigned short* __restrict__ aggr, int n) {
    __shared__ float acc[256 * 128];          // 128 KB
    const int b    = blockIdx.x;
    const int tid  = threadIdx.x;
    const int wid  = tid >> 6;
    const int lane = tid & 63;

    // zero accumulator (bank-spread float4 stores)
#pragma unroll
    for (int j = 0; j < 8; ++j)
        *(float4*)&acc[tid * 4 + j * 4096] = make_float4(0.f, 0.f, 0.f, 0.f);
    __syncthreads();

    int cnt = gcur[b];
    if (cnt > BCAP) cnt = BCAP;
    const int2* pb = part + (size_t)b * BCAP;

    // edge accumulation: wave-per-edge, 4-deep batch
    for (int i = wid * 4; i < cnt; i += 64) {
        int2 r[4];
        float c[4];
        unsigned int hu[4];
#pragma unroll
        for (int j = 0; j < 4; ++j)
            if (i + j < cnt) r[j] = pb[i + j];
#pragma unroll
        for (int j = 0; j < 4; ++j)
            if (i + j < cnt) {
                int s = r[j].x & 0x1FFFF;
                c[j] = dinv[s] * __int_as_float(r[j].y);
                hu[j] = *(const unsigned int*)(h + (size_t)s * 128 + lane * 2);
            }
#pragma unroll
        for (int j = 0; j < 4; ++j)
            if (i + j < cnt) {
                int dl = (r[j].x >> 17) & 255;
                atomicAdd(&acc[dl * 128 + lane * 2], c[j] * bflo(hu[j]));
                atomicAdd(&acc[dl * 128 + lane * 2 + 1], c[j] * bfhi(hu[j]));
            }
    }
    __syncthreads();

    // flush: wave w handles nodes w, w+16, ... (float2 LDS reads, 2-way free)
    float2 bv = *(const float2*)(bias + lane * 2);
    for (int nd = wid; nd < 256; nd += 16) {
        int g = (b << BSHIFT) + nd;
        if (g >= n) break;
        float di = dinv[g];
        float sl = di * di;
        float2 a = *(const float2*)&acc[nd * 128 + lane * 2];
        unsigned int hu = *(const unsigned int*)(h + (size_t)g * 128 + lane * 2);
        float ox = frelu(di * a.x + sl * bflo(hu) + bv.x);
        float oy = frelu(di * a.y + sl * bfhi(hu) + bv.y);
        unsigned int o = (unsigned int)f2bf(ox) | ((unsigned int)f2bf(oy) << 16);
        *(unsigned int*)(aggr + (size_t)g * 128 + lane * 2) = o;
    }
}

// ---------------- bf16 MFMA GEMM (unchanged) ----------------
template<int K, int RELU, int EPI>
__global__ __launch_bounds__(256, 2) void gemm_bf(
    const unsigned short* __restrict__ A, const unsigned short* __restrict__ Wt,
    const float* __restrict__ bias, void* __restrict__ Cout,
    int M, int nrows, float* __restrict__ xs) {
    constexpr int BM = 128, BN = 64, BK = 64;
    __shared__ unsigned short As[BM][BK + 8];
    __shared__ unsigned short Bs[BN][BK + 8];

    const int tid  = threadIdx.x;
    const int wid  = tid >> 6;
    const int lane = tid & 63;
    const int wm   = (wid >> 1) * 64;
    const int wn   = (wid & 1) * 32;
    const int row0 = blockIdx.x * BM;
    const int col0 = blockIdx.y * BN;
    const int lr   = lane & 15;
    const int lk   = (lane >> 4) * 8;

    f32x4 acc[4][2] = {};

    for (int k0 = 0; k0 < K; k0 += BK) {
#pragma unroll
        for (int it = 0; it < 4; ++it) {
            int f = tid + it * 256;
            int r = f >> 3, g = f & 7;
            int grow = row0 + r;
            if (grow >= nrows) grow = nrows - 1;
            bf16x8 v = *(const bf16x8*)(A + (size_t)grow * K + k0 + g * 8);
            *(bf16x8*)&As[r][g * 8] = v;
        }
#pragma unroll
        for (int it = 0; it < 2; ++it) {
            int f = tid + it * 256;
            int nidx = f >> 3, g = f & 7;
            bf16x8 v = *(const bf16x8*)(Wt + (size_t)(col0 + nidx) * K + k0 + g * 8);
            *(bf16x8*)&Bs[nidx][g * 8] = v;
        }
        __syncthreads();
#pragma unroll
        for (int kk = 0; kk < 2; ++kk) {
            bf16x8 af[4], bfv[2];
#pragma unroll
            for (int mi = 0; mi < 4; ++mi)
                af[mi] = *(const bf16x8*)&As[wm + 16 * mi + lr][kk * 32 + lk];
#pragma unroll
            for (int ni = 0; ni < 2; ++ni)
                bfv[ni] = *(const bf16x8*)&Bs[wn + 16 * ni + lr][kk * 32 + lk];
#pragma unroll
            for (int mi = 0; mi < 4; ++mi)
#pragma unroll
                for (int ni = 0; ni < 2; ++ni)
                    acc[mi][ni] = __builtin_amdgcn_mfma_f32_16x16x32_bf16(
                        af[mi], bfv[ni], acc[mi][ni], 0, 0, 0);
        }
        __syncthreads();
    }

    const int dr0 = (lane >> 4) * 4;
#pragma unroll
    for (int ni = 0; ni < 2; ++ni) {
        int col = col0 + wn + 16 * ni + lr;
        float bv = bias ? bias[col] : 0.f;
#pragma unroll
        for (int mi = 0; mi < 4; ++mi) {
#pragma unroll
            for (int r = 0; r < 4; ++r) {
                int grow = row0 + wm + 16 * mi + dr0 + r;
                if (grow >= nrows) continue;
                float v = acc[mi][ni][r] + bv;
                if (RELU) v = frelu(v);
                if (EPI == 0) {
                    ((unsigned short*)Cout)[(size_t)grow * M + col] = f2bf(v);
                } else {
                    ((float*)Cout)[(size_t)grow * M + col] = v;
                    if (EPI == 2) xs[(size_t)grow * 64 + col] += v;
                }
            }
        }
    }
}

// ---------------------------------------------------------------------------
extern "C" void kernel_launch(void* const* d_in, const int* in_sizes, int n_in,
                              void* d_out, int out_size, void* d_ws, size_t ws_size,
                              hipStream_t stream) {
    (void)n_in; (void)out_size; (void)ws_size;
    const float* X = (const float*)d_in[0];
    const int N = in_sizes[0] / 128;

    const float* fc1_w1 = (const float*)d_in[19];
    const float* fc1_b1 = (const float*)d_in[20];
    const float* fc1_w2 = (const float*)d_in[21];
    const float* fc1_b2 = (const float*)d_in[22];
    const float* fc1_w3 = (const float*)d_in[23];
    const float* fc1_b3 = (const float*)d_in[24];
    const float* fc2_w1 = (const float*)d_in[25];
    const float* fc2_b1 = (const float*)d_in[26];
    const float* fc2_w2 = (const float*)d_in[27];
    const float* fc2_b2 = (const float*)d_in[28];
    const float* fc2_w3 = (const float*)d_in[29];
    const float* fc2_b3 = (const float*)d_in[30];

    float* out = (float*)d_out;
    float* Xs  = out;  // slot 0

    // ---- workspace layout ----
    char* base = (char*)d_ws;
    const size_t Npad = (((size_t)N + 255) / 256) * 256;
    float*          dinv  = (float*)base;                 base += Npad * 4;
    unsigned short* Xbf   = (unsigned short*)base;        base += (size_t)N * 128 * 2;
    unsigned short* t1bf  = (unsigned short*)base;        base += (size_t)N * 256 * 2;  // bucket arena alias
    unsigned short* t2bf  = (unsigned short*)base;        base += (size_t)N * 128 * 2;
    unsigned short* aggbf = (unsigned short*)base;        base += (size_t)N * 128 * 2;
    unsigned short* wtbuf = (unsigned short*)base;

    unsigned short* fc1w1t = wtbuf;
    unsigned short* fc1w2t = fc1w1t + 32768;
    unsigned short* fc1w3t = fc1w2t + 32768;
    unsigned short* fc2w1t = fc1w3t + 8192;
    unsigned short* fc2w2t = fc2w1t + 32768;
    unsigned short* fc2w3t = fc2w2t + 32768;
    unsigned short* gwt    = fc2w3t + 8192;

    const dim3 blk(256);
    const int GR = (N + 127) / 128;
    const int NBUCK = (N + 255) >> 8;     // 391 for N=100000

    // ---- one-time conversions ----
    xconv<<<(N * 32 + 255) / 256, blk, 0, stream>>>(X, Xbf, N * 32);
    wtrans<<<(128 * 256 + 255) / 256, blk, 0, stream>>>(fc1_w1, fc1w1t, 128, 256);
    wtrans<<<(256 * 128 + 255) / 256, blk, 0, stream>>>(fc1_w2, fc1w2t, 256, 128);
    wtrans<<<(128 * 64 + 255) / 256, blk, 0, stream>>>(fc1_w3, fc1w3t, 128, 64);
    wtrans<<<(128 * 256 + 255) / 256, blk, 0, stream>>>(fc2_w1, fc2w1t, 128, 256);
    wtrans<<<(256 * 128 + 255) / 256, blk, 0, stream>>>(fc2_w2, fc2w2t, 256, 128);
    wtrans<<<(128 * 64 + 255) / 256, blk, 0, stream>>>(fc2_w3, fc2w3t, 128, 64);
    for (int g = 0; g < 3; ++g) {
        wtrans<<<(128 * 128 + 255) / 256, blk, 0, stream>>>(
            (const float*)d_in[3 + 6 * g], gwt + g * 32768, 128, 128);
        wtrans<<<(128 * 128 + 255) / 256, blk, 0, stream>>>(
            (const float*)d_in[5 + 6 * g], gwt + g * 32768 + 16384, 128, 128);
    }

    // ---- X0 = fc1(X) -> Xs ----
    gemm_bf<128, 1, 0><<<dim3(GR, 4), blk, 0, stream>>>(Xbf, fc1w1t, fc1_b1, t1bf, 256, N, nullptr);
    gemm_bf<256, 1, 0><<<dim3(GR, 2), blk, 0, stream>>>(t1bf, fc1w2t, fc1_b2, t2bf, 128, N, nullptr);
    gemm_bf<128, 1, 1><<<dim3(GR, 1), blk, 0, stream>>>(t2bf, fc1w3t, fc1_b3, Xs, 64, N, nullptr);

    // ---- graphs ----
    for (int g = 0; g < 3; ++g) {
        const int*   ei  = (const int*)d_in[1 + 6 * g];
        const int    E   = in_sizes[1 + 6 * g] / 2;
        const int*   srp = ei;
        const int*   dsp = ei + E;
        const float* ew  = (const float*)d_in[2 + 6 * g];
        const float* b1  = (const float*)d_in[4 + 6 * g];
        const float* b2  = (const float*)d_in[6 + 6 * g];
        unsigned short* w1t = gwt + g * 32768;
        unsigned short* w2t = w1t + 16384;

        // bucket arena aliases t1bf (dead during conv phase)
        int2* part = (int2*)t1bf;                      // NBUCK * BCAP (19.2 MB)
        int*  gcur = (int*)(part + (size_t)NBUCK * BCAP);  // NBUCK

        zero_small<<<(NBUCK + 255) / 256, blk, 0, stream>>>(gcur, NBUCK);   // FIX: cover all buckets
        part_k<<<(E + 4095) / 4096, blk, 0, stream>>>(srp, dsp, ew, gcur, part, E, NBUCK);
        deg_bucket<<<NBUCK, blk, 0, stream>>>(part, gcur, dinv, N);

        // conv1 + conv2 (agg applies dinv scaling + self-loop + bias + relu)
        gemm_bf<128, 0, 0><<<dim3(GR, 2), blk, 0, stream>>>(Xbf, w1t, nullptr, t2bf, 128, N, nullptr);
        agg_bucket<<<NBUCK, 1024, 0, stream>>>(part, gcur, t2bf, dinv, b1, aggbf, N);
        gemm_bf<128, 0, 0><<<dim3(GR, 2), blk, 0, stream>>>(aggbf, w2t, nullptr, t2bf, 128, N, nullptr);
        agg_bucket<<<NBUCK, 1024, 0, stream>>>(part, gcur, t2bf, dinv, b2, aggbf, N);

        // fc2 head
        gemm_bf<128, 1, 0><<<dim3(GR, 4), blk, 0, stream>>>(aggbf, fc2w1t, fc2_b1, t1bf, 256, N, nullptr);
        gemm_bf<256, 1, 0><<<dim3(GR, 2), blk, 0, stream>>>(t1bf, fc2w2t, fc2_b2, t2bf, 128, N, nullptr);
        gemm_bf<128, 1, 2><<<dim3(GR, 1), blk, 0, stream>>>(
            t2bf, fc2w3t, fc2_b3, out + (size_t)(1 + g) * N * 64, 64, N, Xs);
    }
}

// Round 8
// 1182.741 us; speedup vs baseline: 7.4846x; 7.4846x over previous
//
#include <hip/hip_runtime.h>

// ---------------------------------------------------------------------------
// SubModel_22016002359901: 3x GCN(2 conv) + FC heads, N=100000, F=128, E=1.6M
// Round 8: round-4 structure (CSR + wave-per-node gather + bf16 MFMA GEMMs)
// with the CSR build replaced by: bucketed partition (part_k) -> per-bucket
// LDS counting sort (csr_bucket, INT LDS atomics only; fixed-point weighted
// degree fused into the scatter pass). deg_cnt_p / place_k / normfix deleted.
// Gather applies dinv[src] per edge (broadcast load) and dinv[dst] at flush.
// ---------------------------------------------------------------------------

typedef short bf16x8 __attribute__((ext_vector_type(8)));
typedef float f32x4 __attribute__((ext_vector_type(4)));

#define BSHIFT 8                 // 256 dst nodes per bucket
#define NBUCK_MAX 400
#define BCAP 6144                // mean 4096 @ E=1.6M, sigma ~64 -> 32 sigma headroom
#define WDSCALE 8388608.f        // 2^23 fixed-point for weighted degree

static __device__ __forceinline__ float frelu(float x) { return x > 0.f ? x : 0.f; }

static __device__ __forceinline__ unsigned short f2bf(float f) {
    unsigned int u = __float_as_uint(f);
    u += 0x7fffu + ((u >> 16) & 1u);           // RNE
    return (unsigned short)(u >> 16);
}
static __device__ __forceinline__ float bflo(unsigned int u) {
    return __uint_as_float(u << 16);
}
static __device__ __forceinline__ float bfhi(unsigned int u) {
    return __uint_as_float(u & 0xffff0000u);
}

// ---------------- conversion kernels ----------------
__global__ void xconv(const float* __restrict__ src, unsigned short* __restrict__ dst, int n4) {
    int i = blockIdx.x * 256 + threadIdx.x;
    if (i >= n4) return;
    float4 v = *(const float4*)(src + (size_t)i * 4);
    ushort4 o = {f2bf(v.x), f2bf(v.y), f2bf(v.z), f2bf(v.w)};
    *(ushort4*)(dst + (size_t)i * 4) = o;
}

__global__ void wtrans(const float* __restrict__ src, unsigned short* __restrict__ dst,
                       int K, int M) {
    int i = blockIdx.x * 256 + threadIdx.x;
    if (i >= K * M) return;
    int m = i / K, k = i % K;
    dst[i] = f2bf(src[(size_t)k * M + m]);
}

__global__ void zero_small(int* __restrict__ p, int n) {
    int i = blockIdx.x * 256 + threadIdx.x;
    if (i < n) p[i] = 0;
}

// ---------------- bucketed edge partition ----------------
// record = {src | dstlocal<<17, ew}; bucket = dst>>8
__global__ __launch_bounds__(256) void part_k(
    const int* __restrict__ src, const int* __restrict__ dst,
    const float* __restrict__ ew, int* __restrict__ gcur,
    int2* __restrict__ part, int nE, int nbuck) {
    __shared__ int lh[NBUCK_MAX];
    __shared__ int gb[NBUCK_MAX];
    const int tid = threadIdx.x;
    for (int t = tid; t < nbuck; t += 256) lh[t] = 0;
    __syncthreads();
    const int e0 = blockIdx.x * 4096;
    int rk[16], bk[16];
#pragma unroll
    for (int j = 0; j < 16; ++j) {
        int e = e0 + j * 256 + tid;
        rk[j] = -1;
        if (e < nE) {
            int b = dst[e] >> BSHIFT;
            bk[j] = b;
            rk[j] = atomicAdd(&lh[b], 1);
        }
    }
    __syncthreads();
    for (int t = tid; t < nbuck; t += 256)
        gb[t] = lh[t] ? atomicAdd(&gcur[t], lh[t]) : 0;
    __syncthreads();
#pragma unroll
    for (int j = 0; j < 16; ++j) {
        int e = e0 + j * 256 + tid;
        if (e >= nE) continue;
        int b = bk[j];
        int slot = gb[b] + rk[j];
        if (slot >= 0 && slot < BCAP) {
            int s = src[e];
            int dl = dst[e] & ((1 << BSHIFT) - 1);
            part[(size_t)b * BCAP + slot] = make_int2(s | (dl << 17), __float_as_int(ew[e]));
        }
    }
}

// exclusive scan of clamped bucket counts -> bbase; rp[n] = total
__global__ void scanB(const int* __restrict__ gcur, int* __restrict__ bbase,
                      int* __restrict__ rp, int n, int nbuck) {
    __shared__ int s[512];
    int t = threadIdx.x;
    int c = (t < nbuck) ? gcur[t] : 0;
    if (c > BCAP) c = BCAP;
    s[t] = c;
    __syncthreads();
#pragma unroll
    for (int off = 1; off < 512; off <<= 1) {
        int x = (t >= off) ? s[t - off] : 0;
        __syncthreads();
        s[t] += x;
        __syncthreads();
    }
    if (t < nbuck) bbase[t] = s[t] - c;        // exclusive
    if (t == nbuck - 1) rp[n] = s[t];          // total (== E unless overflow)
}

// one 256-thread block per bucket: LDS counting sort by dstlocal ->
// ev records {src, ew} grouped per node; fixed-point weighted degree fused
// into scatter pass -> dinv; rp per node.
__global__ __launch_bounds__(256) void csr_bucket(
    const int2* __restrict__ part, const int* __restrict__ gcur,
    const int* __restrict__ bbase, int2* __restrict__ ev,
    int* __restrict__ rp, float* __restrict__ dinv, int n) {
    __shared__ int hist[256];
    __shared__ int cur[256];
    __shared__ int wd[256];
    const int b = blockIdx.x;
    const int t = threadIdx.x;
    int cnt = gcur[b];
    if (cnt > BCAP) cnt = BCAP;
    const int gbase = bbase[b];
    const int2* pb = part + (size_t)b * BCAP;

    hist[t] = 0; wd[t] = 0;
    __syncthreads();
    for (int i = t; i < cnt; i += 256)
        atomicAdd(&hist[(pb[i].x >> 17) & 255], 1);
    __syncthreads();
    int myh = hist[t];
    // inclusive scan of hist
#pragma unroll
    for (int off = 1; off < 256; off <<= 1) {
        int x = (t >= off) ? hist[t - off] : 0;
        __syncthreads();
        hist[t] += x;
        __syncthreads();
    }
    int excl = hist[t] - myh;
    cur[t] = excl;
    __syncthreads();
    // scatter into per-node runs + accumulate fixed-point weighted degree
    for (int i = t; i < cnt; i += 256) {
        int2 p = pb[i];
        int dl = (p.x >> 17) & 255;
        int pos = atomicAdd(&cur[dl], 1);
        ev[(size_t)gbase + pos] = make_int2(p.x & 0x1FFFF, p.y);
        atomicAdd(&wd[dl], (int)(__int_as_float(p.y) * WDSCALE + 0.5f));
    }
    __syncthreads();
    int g = (b << BSHIFT) + t;
    if (g < n) {
        dinv[g] = rsqrtf(1.f + (float)wd[t] * (1.f / WDSCALE));
        rp[g] = gbase + excl;
    }
}

// one wave per node: aggr = relu( dinv[n]*sum(dinv[src]*ew*h[src])
//                                 + dinv[n]^2*h[n] + bias ), bf16 in/out
__global__ __launch_bounds__(256) void gather_bf(
    const int* __restrict__ rp, const int2* __restrict__ ev,
    const unsigned short* __restrict__ h,
    const float* __restrict__ dinv, const float* __restrict__ bias,
    unsigned short* __restrict__ aggr, int n) {
    int node = (int)(((size_t)blockIdx.x * 256 + threadIdx.x) >> 6);
    if (node >= n) return;
    int lane = threadIdx.x & 63;
    float di = dinv[node];
    float sl = di * di;
    unsigned int hu = *(const unsigned int*)(h + (size_t)node * 128 + lane * 2);
    float2 bv = *(const float2*)(bias + lane * 2);
    float a0x = 0.f, a0y = 0.f, a1x = 0.f, a1y = 0.f;
    float a2x = 0.f, a2y = 0.f, a3x = 0.f, a3y = 0.f;
    int beg = rp[node], end = rp[node + 1];
    int i = beg;
    for (; i + 3 < end; i += 4) {
        int2 e0 = ev[i], e1 = ev[i + 1], e2 = ev[i + 2], e3 = ev[i + 3];
        float n0 = dinv[e0.x] * __int_as_float(e0.y);
        float n1 = dinv[e1.x] * __int_as_float(e1.y);
        float n2 = dinv[e2.x] * __int_as_float(e2.y);
        float n3 = dinv[e3.x] * __int_as_float(e3.y);
        unsigned int u0 = *(const unsigned int*)(h + (size_t)e0.x * 128 + lane * 2);
        unsigned int u1 = *(const unsigned int*)(h + (size_t)e1.x * 128 + lane * 2);
        unsigned int u2 = *(const unsigned int*)(h + (size_t)e2.x * 128 + lane * 2);
        unsigned int u3 = *(const unsigned int*)(h + (size_t)e3.x * 128 + lane * 2);
        a0x += n0 * bflo(u0); a0y += n0 * bfhi(u0);
        a1x += n1 * bflo(u1); a1y += n1 * bfhi(u1);
        a2x += n2 * bflo(u2); a2y += n2 * bfhi(u2);
        a3x += n3 * bflo(u3); a3y += n3 * bfhi(u3);
    }
    for (; i < end; ++i) {
        int2 e0 = ev[i];
        float n0 = dinv[e0.x] * __int_as_float(e0.y);
        unsigned int u0 = *(const unsigned int*)(h + (size_t)e0.x * 128 + lane * 2);
        a0x += n0 * bflo(u0); a0y += n0 * bfhi(u0);
    }
    float ox = frelu(di * ((a0x + a1x) + (a2x + a3x)) + sl * bflo(hu) + bv.x);
    float oy = frelu(di * ((a0y + a1y) + (a2y + a3y)) + sl * bfhi(hu) + bv.y);
    unsigned int o = (unsigned int)f2bf(ox) | ((unsigned int)f2bf(oy) << 16);
    *(unsigned int*)(aggr + (size_t)node * 128 + lane * 2) = o;
}

// ---------------- bf16 MFMA GEMM (unchanged) ----------------
template<int K, int RELU, int EPI>
__global__ __launch_bounds__(256, 2) void gemm_bf(
    const unsigned short* __restrict__ A, const unsigned short* __restrict__ Wt,
    const float* __restrict__ bias, void* __restrict__ Cout,
    int M, int nrows, float* __restrict__ xs) {
    constexpr int BM = 128, BN = 64, BK = 64;
    __shared__ unsigned short As[BM][BK + 8];
    __shared__ unsigned short Bs[BN][BK + 8];

    const int tid  = threadIdx.x;
    const int wid  = tid >> 6;
    const int lane = tid & 63;
    const int wm   = (wid >> 1) * 64;
    const int wn   = (wid & 1) * 32;
    const int row0 = blockIdx.x * BM;
    const int col0 = blockIdx.y * BN;
    const int lr   = lane & 15;
    const int lk   = (lane >> 4) * 8;

    f32x4 acc[4][2] = {};

    for (int k0 = 0; k0 < K; k0 += BK) {
#pragma unroll
        for (int it = 0; it < 4; ++it) {
            int f = tid + it * 256;
            int r = f >> 3, g = f & 7;
            int grow = row0 + r;
            if (grow >= nrows) grow = nrows - 1;
            bf16x8 v = *(const bf16x8*)(A + (size_t)grow * K + k0 + g * 8);
            *(bf16x8*)&As[r][g * 8] = v;
        }
#pragma unroll
        for (int it = 0; it < 2; ++it) {
            int f = tid + it * 256;
            int nidx = f >> 3, g = f & 7;
            bf16x8 v = *(const bf16x8*)(Wt + (size_t)(col0 + nidx) * K + k0 + g * 8);
            *(bf16x8*)&Bs[nidx][g * 8] = v;
        }
        __syncthreads();
#pragma unroll
        for (int kk = 0; kk < 2; ++kk) {
            bf16x8 af[4], bfv[2];
#pragma unroll
            for (int mi = 0; mi < 4; ++mi)
                af[mi] = *(const bf16x8*)&As[wm + 16 * mi + lr][kk * 32 + lk];
#pragma unroll
            for (int ni = 0; ni < 2; ++ni)
                bfv[ni] = *(const bf16x8*)&Bs[wn + 16 * ni + lr][kk * 32 + lk];
#pragma unroll
            for (int mi = 0; mi < 4; ++mi)
#pragma unroll
                for (int ni = 0; ni < 2; ++ni)
                    acc[mi][ni] = __builtin_amdgcn_mfma_f32_16x16x32_bf16(
                        af[mi], bfv[ni], acc[mi][ni], 0, 0, 0);
        }
        __syncthreads();
    }

    const int dr0 = (lane >> 4) * 4;
#pragma unroll
    for (int ni = 0; ni < 2; ++ni) {
        int col = col0 + wn + 16 * ni + lr;
        float bv = bias ? bias[col] : 0.f;
#pragma unroll
        for (int mi = 0; mi < 4; ++mi) {
#pragma unroll
            for (int r = 0; r < 4; ++r) {
                int grow = row0 + wm + 16 * mi + dr0 + r;
                if (grow >= nrows) continue;
                float v = acc[mi][ni][r] + bv;
                if (RELU) v = frelu(v);
                if (EPI == 0) {
                    ((unsigned short*)Cout)[(size_t)grow * M + col] = f2bf(v);
                } else {
                    ((float*)Cout)[(size_t)grow * M + col] = v;
                    if (EPI == 2) xs[(size_t)grow * 64 + col] += v;
                }
            }
        }
    }
}

// ---------------------------------------------------------------------------
extern "C" void kernel_launch(void* const* d_in, const int* in_sizes, int n_in,
                              void* d_out, int out_size, void* d_ws, size_t ws_size,
                              hipStream_t stream) {
    (void)n_in; (void)out_size; (void)ws_size;
    const float* X = (const float*)d_in[0];
    const int N = in_sizes[0] / 128;

    const float* fc1_w1 = (const float*)d_in[19];
    const float* fc1_b1 = (const float*)d_in[20];
    const float* fc1_w2 = (const float*)d_in[21];
    const float* fc1_b2 = (const float*)d_in[22];
    const float* fc1_w3 = (const float*)d_in[23];
    const float* fc1_b3 = (const float*)d_in[24];
    const float* fc2_w1 = (const float*)d_in[25];
    const float* fc2_b1 = (const float*)d_in[26];
    const float* fc2_w2 = (const float*)d_in[27];
    const float* fc2_b2 = (const float*)d_in[28];
    const float* fc2_w3 = (const float*)d_in[29];
    const float* fc2_b3 = (const float*)d_in[30];

    float* out = (float*)d_out;
    float* Xs  = out;  // slot 0

    // ---- workspace layout ----
    char* base = (char*)d_ws;
    const size_t Npad = (((size_t)N + 255) / 256) * 256;
    float*          dinv  = (float*)base;                 base += Npad * 4;
    unsigned short* Xbf   = (unsigned short*)base;        base += (size_t)N * 128 * 2;
    unsigned short* t1bf  = (unsigned short*)base;        base += (size_t)N * 256 * 2;  // CSR arena alias
    unsigned short* t2bf  = (unsigned short*)base;        base += (size_t)N * 128 * 2;
    unsigned short* aggbf = (unsigned short*)base;        base += (size_t)N * 128 * 2;
    unsigned short* wtbuf = (unsigned short*)base;

    unsigned short* fc1w1t = wtbuf;
    unsigned short* fc1w2t = fc1w1t + 32768;
    unsigned short* fc1w3t = fc1w2t + 32768;
    unsigned short* fc2w1t = fc1w3t + 8192;
    unsigned short* fc2w2t = fc2w1t + 32768;
    unsigned short* fc2w3t = fc2w2t + 32768;
    unsigned short* gwt    = fc2w3t + 8192;

    const dim3 blk(256);
    const int GR = (N + 127) / 128;
    const int NBUCK = (N + 255) >> 8;     // 391 for N=100000
    const int GWB = (int)(((size_t)N * 64 + 255) / 256);

    // ---- one-time conversions ----
    xconv<<<(N * 32 + 255) / 256, blk, 0, stream>>>(X, Xbf, N * 32);
    wtrans<<<(128 * 256 + 255) / 256, blk, 0, stream>>>(fc1_w1, fc1w1t, 128, 256);
    wtrans<<<(256 * 128 + 255) / 256, blk, 0, stream>>>(fc1_w2, fc1w2t, 256, 128);
    wtrans<<<(128 * 64 + 255) / 256, blk, 0, stream>>>(fc1_w3, fc1w3t, 128, 64);
    wtrans<<<(128 * 256 + 255) / 256, blk, 0, stream>>>(fc2_w1, fc2w1t, 128, 256);
    wtrans<<<(256 * 128 + 255) / 256, blk, 0, stream>>>(fc2_w2, fc2w2t, 256, 128);
    wtrans<<<(128 * 64 + 255) / 256, blk, 0, stream>>>(fc2_w3, fc2w3t, 128, 64);
    for (int g = 0; g < 3; ++g) {
        wtrans<<<(128 * 128 + 255) / 256, blk, 0, stream>>>(
            (const float*)d_in[3 + 6 * g], gwt + g * 32768, 128, 128);
        wtrans<<<(128 * 128 + 255) / 256, blk, 0, stream>>>(
            (const float*)d_in[5 + 6 * g], gwt + g * 32768 + 16384, 128, 128);
    }

    // ---- X0 = fc1(X) -> Xs ----
    gemm_bf<128, 1, 0><<<dim3(GR, 4), blk, 0, stream>>>(Xbf, fc1w1t, fc1_b1, t1bf, 256, N, nullptr);
    gemm_bf<256, 1, 0><<<dim3(GR, 2), blk, 0, stream>>>(t1bf, fc1w2t, fc1_b2, t2bf, 128, N, nullptr);
    gemm_bf<128, 1, 1><<<dim3(GR, 1), blk, 0, stream>>>(t2bf, fc1w3t, fc1_b3, Xs, 64, N, nullptr);

    // ---- graphs ----
    for (int g = 0; g < 3; ++g) {
        const int*   ei  = (const int*)d_in[1 + 6 * g];
        const int    E   = in_sizes[1 + 6 * g] / 2;
        const int*   srp = ei;
        const int*   dsp = ei + E;
        const float* ew  = (const float*)d_in[2 + 6 * g];
        const float* b1  = (const float*)d_in[4 + 6 * g];
        const float* b2  = (const float*)d_in[6 + 6 * g];
        unsigned short* w1t = gwt + g * 32768;
        unsigned short* w2t = w1t + 16384;

        // CSR arena aliases t1bf (dead during conv phase)
        int2* part  = (int2*)t1bf;                        // NBUCK * BCAP  (19.2 MB)
        int2* ev    = part + (size_t)NBUCK * BCAP;        // E             (12.8 MB)
        int*  rpn   = (int*)(ev + E);                     // N+1
        int*  gcur  = rpn + (N + 1);                      // NBUCK
        int*  bbase = gcur + NBUCK;                       // NBUCK

        zero_small<<<(NBUCK + 255) / 256, blk, 0, stream>>>(gcur, NBUCK);
        part_k<<<(E + 4095) / 4096, blk, 0, stream>>>(srp, dsp, ew, gcur, part, E, NBUCK);
        scanB<<<1, 512, 0, stream>>>(gcur, bbase, rpn, N, NBUCK);
        csr_bucket<<<NBUCK, blk, 0, stream>>>(part, gcur, bbase, ev, rpn, dinv, N);

        // conv1 + conv2 (gather applies dinv scaling + self-loop + bias + relu)
        gemm_bf<128, 0, 0><<<dim3(GR, 2), blk, 0, stream>>>(Xbf, w1t, nullptr, t2bf, 128, N, nullptr);
        gather_bf<<<GWB, blk, 0, stream>>>(rpn, ev, t2bf, dinv, b1, aggbf, N);
        gemm_bf<128, 0, 0><<<dim3(GR, 2), blk, 0, stream>>>(aggbf, w2t, nullptr, t2bf, 128, N, nullptr);
        gather_bf<<<GWB, blk, 0, stream>>>(rpn, ev, t2bf, dinv, b2, aggbf, N);

        // fc2 head
        gemm_bf<128, 1, 0><<<dim3(GR, 4), blk, 0, stream>>>(aggbf, fc2w1t, fc2_b1, t1bf, 256, N, nullptr);
        gemm_bf<256, 1, 0><<<dim3(GR, 2), blk, 0, stream>>>(t1bf, fc2w2t, fc2_b2, t2bf, 128, N, nullptr);
        gemm_bf<128, 1, 2><<<dim3(GR, 1), blk, 0, stream>>>(
            t2bf, fc2w3t, fc2_b3, out + (size_t)(1 + g) * N * 64, 64, N, Xs);
    }
}

// Round 9
// 1133.020 us; speedup vs baseline: 7.8130x; 1.0439x over previous
//
#include <hip/hip_runtime.h>

// ---------------------------------------------------------------------------
// SubModel_22016002359901: 3x GCN(2 conv) + FC heads, N=100000, F=128, E=1.6M
// Round 9: GEMM tile widened to BN=128 (acc[4][4]/wave, 36.9KB LDS,
// single-pass over A for all M>=128 GEMMs -- was reading A 2-4x with BN=64).
// CSR build + gather unchanged from round 8.
// ---------------------------------------------------------------------------

typedef short bf16x8 __attribute__((ext_vector_type(8)));
typedef float f32x4 __attribute__((ext_vector_type(4)));

#define BSHIFT 8                 // 256 dst nodes per bucket
#define NBUCK_MAX 400
#define BCAP 6144                // mean 4096 @ E=1.6M, sigma ~64 -> 32 sigma headroom
#define WDSCALE 8388608.f        // 2^23 fixed-point for weighted degree

static __device__ __forceinline__ float frelu(float x) { return x > 0.f ? x : 0.f; }

static __device__ __forceinline__ unsigned short f2bf(float f) {
    unsigned int u = __float_as_uint(f);
    u += 0x7fffu + ((u >> 16) & 1u);           // RNE
    return (unsigned short)(u >> 16);
}
static __device__ __forceinline__ float bflo(unsigned int u) {
    return __uint_as_float(u << 16);
}
static __device__ __forceinline__ float bfhi(unsigned int u) {
    return __uint_as_float(u & 0xffff0000u);
}

// ---------------- conversion kernels ----------------
__global__ void xconv(const float* __restrict__ src, unsigned short* __restrict__ dst, int n4) {
    int i = blockIdx.x * 256 + threadIdx.x;
    if (i >= n4) return;
    float4 v = *(const float4*)(src + (size_t)i * 4);
    ushort4 o = {f2bf(v.x), f2bf(v.y), f2bf(v.z), f2bf(v.w)};
    *(ushort4*)(dst + (size_t)i * 4) = o;
}

__global__ void wtrans(const float* __restrict__ src, unsigned short* __restrict__ dst,
                       int K, int M) {
    int i = blockIdx.x * 256 + threadIdx.x;
    if (i >= K * M) return;
    int m = i / K, k = i % K;
    dst[i] = f2bf(src[(size_t)k * M + m]);
}

__global__ void zero_small(int* __restrict__ p, int n) {
    int i = blockIdx.x * 256 + threadIdx.x;
    if (i < n) p[i] = 0;
}

// ---------------- bucketed edge partition ----------------
// record = {src | dstlocal<<17, ew}; bucket = dst>>8
__global__ __launch_bounds__(256) void part_k(
    const int* __restrict__ src, const int* __restrict__ dst,
    const float* __restrict__ ew, int* __restrict__ gcur,
    int2* __restrict__ part, int nE, int nbuck) {
    __shared__ int lh[NBUCK_MAX];
    __shared__ int gb[NBUCK_MAX];
    const int tid = threadIdx.x;
    for (int t = tid; t < nbuck; t += 256) lh[t] = 0;
    __syncthreads();
    const int e0 = blockIdx.x * 4096;
    int rk[16], bk[16];
#pragma unroll
    for (int j = 0; j < 16; ++j) {
        int e = e0 + j * 256 + tid;
        rk[j] = -1;
        if (e < nE) {
            int b = dst[e] >> BSHIFT;
            bk[j] = b;
            rk[j] = atomicAdd(&lh[b], 1);
        }
    }
    __syncthreads();
    for (int t = tid; t < nbuck; t += 256)
        gb[t] = lh[t] ? atomicAdd(&gcur[t], lh[t]) : 0;
    __syncthreads();
#pragma unroll
    for (int j = 0; j < 16; ++j) {
        int e = e0 + j * 256 + tid;
        if (e >= nE) continue;
        int b = bk[j];
        int slot = gb[b] + rk[j];
        if (slot >= 0 && slot < BCAP) {
            int s = src[e];
            int dl = dst[e] & ((1 << BSHIFT) - 1);
            part[(size_t)b * BCAP + slot] = make_int2(s | (dl << 17), __float_as_int(ew[e]));
        }
    }
}

// exclusive scan of clamped bucket counts -> bbase; rp[n] = total
__global__ void scanB(const int* __restrict__ gcur, int* __restrict__ bbase,
                      int* __restrict__ rp, int n, int nbuck) {
    __shared__ int s[512];
    int t = threadIdx.x;
    int c = (t < nbuck) ? gcur[t] : 0;
    if (c > BCAP) c = BCAP;
    s[t] = c;
    __syncthreads();
#pragma unroll
    for (int off = 1; off < 512; off <<= 1) {
        int x = (t >= off) ? s[t - off] : 0;
        __syncthreads();
        s[t] += x;
        __syncthreads();
    }
    if (t < nbuck) bbase[t] = s[t] - c;        // exclusive
    if (t == nbuck - 1) rp[n] = s[t];          // total (== E unless overflow)
}

// one 256-thread block per bucket: LDS counting sort by dstlocal ->
// ev records {src, ew}; fixed-point weighted degree fused -> dinv; rp.
__global__ __launch_bounds__(256) void csr_bucket(
    const int2* __restrict__ part, const int* __restrict__ gcur,
    const int* __restrict__ bbase, int2* __restrict__ ev,
    int* __restrict__ rp, float* __restrict__ dinv, int n) {
    __shared__ int hist[256];
    __shared__ int cur[256];
    __shared__ int wd[256];
    const int b = blockIdx.x;
    const int t = threadIdx.x;
    int cnt = gcur[b];
    if (cnt > BCAP) cnt = BCAP;
    const int gbase = bbase[b];
    const int2* pb = part + (size_t)b * BCAP;

    hist[t] = 0; wd[t] = 0;
    __syncthreads();
    for (int i = t; i < cnt; i += 256)
        atomicAdd(&hist[(pb[i].x >> 17) & 255], 1);
    __syncthreads();
    int myh = hist[t];
#pragma unroll
    for (int off = 1; off < 256; off <<= 1) {
        int x = (t >= off) ? hist[t - off] : 0;
        __syncthreads();
        hist[t] += x;
        __syncthreads();
    }
    int excl = hist[t] - myh;
    cur[t] = excl;
    __syncthreads();
    for (int i = t; i < cnt; i += 256) {
        int2 p = pb[i];
        int dl = (p.x >> 17) & 255;
        int pos = atomicAdd(&cur[dl], 1);
        ev[(size_t)gbase + pos] = make_int2(p.x & 0x1FFFF, p.y);
        atomicAdd(&wd[dl], (int)(__int_as_float(p.y) * WDSCALE + 0.5f));
    }
    __syncthreads();
    int g = (b << BSHIFT) + t;
    if (g < n) {
        dinv[g] = rsqrtf(1.f + (float)wd[t] * (1.f / WDSCALE));
        rp[g] = gbase + excl;
    }
}

// one wave per node: aggr = relu( dinv[n]*sum(dinv[src]*ew*h[src])
//                                 + dinv[n]^2*h[n] + bias ), bf16 in/out
__global__ __launch_bounds__(256) void gather_bf(
    const int* __restrict__ rp, const int2* __restrict__ ev,
    const unsigned short* __restrict__ h,
    const float* __restrict__ dinv, const float* __restrict__ bias,
    unsigned short* __restrict__ aggr, int n) {
    int node = (int)(((size_t)blockIdx.x * 256 + threadIdx.x) >> 6);
    if (node >= n) return;
    int lane = threadIdx.x & 63;
    float di = dinv[node];
    float sl = di * di;
    unsigned int hu = *(const unsigned int*)(h + (size_t)node * 128 + lane * 2);
    float2 bv = *(const float2*)(bias + lane * 2);
    float a0x = 0.f, a0y = 0.f, a1x = 0.f, a1y = 0.f;
    float a2x = 0.f, a2y = 0.f, a3x = 0.f, a3y = 0.f;
    int beg = rp[node], end = rp[node + 1];
    int i = beg;
    for (; i + 3 < end; i += 4) {
        int2 e0 = ev[i], e1 = ev[i + 1], e2 = ev[i + 2], e3 = ev[i + 3];
        float n0 = dinv[e0.x] * __int_as_float(e0.y);
        float n1 = dinv[e1.x] * __int_as_float(e1.y);
        float n2 = dinv[e2.x] * __int_as_float(e2.y);
        float n3 = dinv[e3.x] * __int_as_float(e3.y);
        unsigned int u0 = *(const unsigned int*)(h + (size_t)e0.x * 128 + lane * 2);
        unsigned int u1 = *(const unsigned int*)(h + (size_t)e1.x * 128 + lane * 2);
        unsigned int u2 = *(const unsigned int*)(h + (size_t)e2.x * 128 + lane * 2);
        unsigned int u3 = *(const unsigned int*)(h + (size_t)e3.x * 128 + lane * 2);
        a0x += n0 * bflo(u0); a0y += n0 * bfhi(u0);
        a1x += n1 * bflo(u1); a1y += n1 * bfhi(u1);
        a2x += n2 * bflo(u2); a2y += n2 * bfhi(u2);
        a3x += n3 * bflo(u3); a3y += n3 * bfhi(u3);
    }
    for (; i < end; ++i) {
        int2 e0 = ev[i];
        float n0 = dinv[e0.x] * __int_as_float(e0.y);
        unsigned int u0 = *(const unsigned int*)(h + (size_t)e0.x * 128 + lane * 2);
        a0x += n0 * bflo(u0); a0y += n0 * bfhi(u0);
    }
    float ox = frelu(di * ((a0x + a1x) + (a2x + a3x)) + sl * bflo(hu) + bv.x);
    float oy = frelu(di * ((a0y + a1y) + (a2y + a3y)) + sl * bfhi(hu) + bv.y);
    unsigned int o = (unsigned int)f2bf(ox) | ((unsigned int)f2bf(oy) << 16);
    *(unsigned int*)(aggr + (size_t)node * 128 + lane * 2) = o;
}

// ---------------- bf16 MFMA GEMM ----------------
// BM=128, BK=64, BN in {64,128}. 4 waves: wave tile 64 x BN/2.
// EPI: 0 = bf16 store; 1 = f32 store; 2 = f32 store + xs[row*64+col] += v.
template<int K, int BN, int RELU, int EPI>
__global__ __launch_bounds__(256, 2) void gemm_bf(
    const unsigned short* __restrict__ A, const unsigned short* __restrict__ Wt,
    const float* __restrict__ bias, void* __restrict__ Cout,
    int M, int nrows, float* __restrict__ xs) {
    constexpr int BM = 128, BK = 64;
    constexpr int WN = BN / 2;        // wave cols
    constexpr int NF = WN / 16;       // col fragments per wave (2 or 4)
    static_assert(BN == 64 || BN == 128, "BN");
    __shared__ unsigned short As[BM][BK + 8];
    __shared__ unsigned short Bs[BN][BK + 8];

    const int tid  = threadIdx.x;
    const int wid  = tid >> 6;
    const int lane = tid & 63;
    const int wm   = (wid >> 1) * 64;
    const int wn   = (wid & 1) * WN;
    const int row0 = blockIdx.x * BM;
    const int col0 = blockIdx.y * BN;
    const int lr   = lane & 15;
    const int lk   = (lane >> 4) * 8;

    f32x4 acc[4][NF] = {};

    for (int k0 = 0; k0 < K; k0 += BK) {
#pragma unroll
        for (int it = 0; it < 4; ++it) {                    // A: 128 rows x 8 granules
            int f = tid + it * 256;
            int r = f >> 3, g = f & 7;
            int grow = row0 + r;
            if (grow >= nrows) grow = nrows - 1;
            bf16x8 v = *(const bf16x8*)(A + (size_t)grow * K + k0 + g * 8);
            *(bf16x8*)&As[r][g * 8] = v;
        }
#pragma unroll
        for (int it = 0; it < BN / 32; ++it) {              // B: BN rows x 8 granules
            int f = tid + it * 256;
            int nidx = f >> 3, g = f & 7;
            bf16x8 v = *(const bf16x8*)(Wt + (size_t)(col0 + nidx) * K + k0 + g * 8);
            *(bf16x8*)&Bs[nidx][g * 8] = v;
        }
        __syncthreads();
#pragma unroll
        for (int kk = 0; kk < 2; ++kk) {
            bf16x8 af[4], bfv[NF];
#pragma unroll
            for (int mi = 0; mi < 4; ++mi)
                af[mi] = *(const bf16x8*)&As[wm + 16 * mi + lr][kk * 32 + lk];
#pragma unroll
            for (int ni = 0; ni < NF; ++ni)
                bfv[ni] = *(const bf16x8*)&Bs[wn + 16 * ni + lr][kk * 32 + lk];
#pragma unroll
            for (int mi = 0; mi < 4; ++mi)
#pragma unroll
                for (int ni = 0; ni < NF; ++ni)
                    acc[mi][ni] = __builtin_amdgcn_mfma_f32_16x16x32_bf16(
                        af[mi], bfv[ni], acc[mi][ni], 0, 0, 0);
        }
        __syncthreads();
    }

    const int dr0 = (lane >> 4) * 4;
#pragma unroll
    for (int ni = 0; ni < NF; ++ni) {
        int col = col0 + wn + 16 * ni + lr;
        float bv = bias ? bias[col] : 0.f;
#pragma unroll
        for (int mi = 0; mi < 4; ++mi) {
#pragma unroll
            for (int r = 0; r < 4; ++r) {
                int grow = row0 + wm + 16 * mi + dr0 + r;
                if (grow >= nrows) continue;
                float v = acc[mi][ni][r] + bv;
                if (RELU) v = frelu(v);
                if (EPI == 0) {
                    ((unsigned short*)Cout)[(size_t)grow * M + col] = f2bf(v);
                } else {
                    ((float*)Cout)[(size_t)grow * M + col] = v;
                    if (EPI == 2) xs[(size_t)grow * 64 + col] += v;
                }
            }
        }
    }
}

// ---------------------------------------------------------------------------
extern "C" void kernel_launch(void* const* d_in, const int* in_sizes, int n_in,
                              void* d_out, int out_size, void* d_ws, size_t ws_size,
                              hipStream_t stream) {
    (void)n_in; (void)out_size; (void)ws_size;
    const float* X = (const float*)d_in[0];
    const int N = in_sizes[0] / 128;

    const float* fc1_w1 = (const float*)d_in[19];
    const float* fc1_b1 = (const float*)d_in[20];
    const float* fc1_w2 = (const float*)d_in[21];
    const float* fc1_b2 = (const float*)d_in[22];
    const float* fc1_w3 = (const float*)d_in[23];
    const float* fc1_b3 = (const float*)d_in[24];
    const float* fc2_w1 = (const float*)d_in[25];
    const float* fc2_b1 = (const float*)d_in[26];
    const float* fc2_w2 = (const float*)d_in[27];
    const float* fc2_b2 = (const float*)d_in[28];
    const float* fc2_w3 = (const float*)d_in[29];
    const float* fc2_b3 = (const float*)d_in[30];

    float* out = (float*)d_out;
    float* Xs  = out;  // slot 0

    // ---- workspace layout ----
    char* base = (char*)d_ws;
    const size_t Npad = (((size_t)N + 255) / 256) * 256;
    float*          dinv  = (float*)base;                 base += Npad * 4;
    unsigned short* Xbf   = (unsigned short*)base;        base += (size_t)N * 128 * 2;
    unsigned short* t1bf  = (unsigned short*)base;        base += (size_t)N * 256 * 2;  // CSR arena alias
    unsigned short* t2bf  = (unsigned short*)base;        base += (size_t)N * 128 * 2;
    unsigned short* aggbf = (unsigned short*)base;        base += (size_t)N * 128 * 2;
    unsigned short* wtbuf = (unsigned short*)base;

    unsigned short* fc1w1t = wtbuf;
    unsigned short* fc1w2t = fc1w1t + 32768;
    unsigned short* fc1w3t = fc1w2t + 32768;
    unsigned short* fc2w1t = fc1w3t + 8192;
    unsigned short* fc2w2t = fc2w1t + 32768;
    unsigned short* fc2w3t = fc2w2t + 32768;
    unsigned short* gwt    = fc2w3t + 8192;

    const dim3 blk(256);
    const int GR = (N + 127) / 128;
    const int NBUCK = (N + 255) >> 8;     // 391 for N=100000
    const int GWB = (int)(((size_t)N * 64 + 255) / 256);

    // ---- one-time conversions ----
    xconv<<<(N * 32 + 255) / 256, blk, 0, stream>>>(X, Xbf, N * 32);
    wtrans<<<(128 * 256 + 255) / 256, blk, 0, stream>>>(fc1_w1, fc1w1t, 128, 256);
    wtrans<<<(256 * 128 + 255) / 256, blk, 0, stream>>>(fc1_w2, fc1w2t, 256, 128);
    wtrans<<<(128 * 64 + 255) / 256, blk, 0, stream>>>(fc1_w3, fc1w3t, 128, 64);
    wtrans<<<(128 * 256 + 255) / 256, blk, 0, stream>>>(fc2_w1, fc2w1t, 128, 256);
    wtrans<<<(256 * 128 + 255) / 256, blk, 0, stream>>>(fc2_w2, fc2w2t, 256, 128);
    wtrans<<<(128 * 64 + 255) / 256, blk, 0, stream>>>(fc2_w3, fc2w3t, 128, 64);
    for (int g = 0; g < 3; ++g) {
        wtrans<<<(128 * 128 + 255) / 256, blk, 0, stream>>>(
            (const float*)d_in[3 + 6 * g], gwt + g * 32768, 128, 128);
        wtrans<<<(128 * 128 + 255) / 256, blk, 0, stream>>>(
            (const float*)d_in[5 + 6 * g], gwt + g * 32768 + 16384, 128, 128);
    }

    // ---- X0 = fc1(X) -> Xs ----
    gemm_bf<128, 128, 1, 0><<<dim3(GR, 2), blk, 0, stream>>>(Xbf, fc1w1t, fc1_b1, t1bf, 256, N, nullptr);
    gemm_bf<256, 128, 1, 0><<<dim3(GR, 1), blk, 0, stream>>>(t1bf, fc1w2t, fc1_b2, t2bf, 128, N, nullptr);
    gemm_bf<128, 64, 1, 1><<<dim3(GR, 1), blk, 0, stream>>>(t2bf, fc1w3t, fc1_b3, Xs, 64, N, nullptr);

    // ---- graphs ----
    for (int g = 0; g < 3; ++g) {
        const int*   ei  = (const int*)d_in[1 + 6 * g];
        const int    E   = in_sizes[1 + 6 * g] / 2;
        const int*   srp = ei;
        const int*   dsp = ei + E;
        const float* ew  = (const float*)d_in[2 + 6 * g];
        const float* b1  = (const float*)d_in[4 + 6 * g];
        const float* b2  = (const float*)d_in[6 + 6 * g];
        unsigned short* w1t = gwt + g * 32768;
        unsigned short* w2t = w1t + 16384;

        // CSR arena aliases t1bf (dead during conv phase)
        int2* part  = (int2*)t1bf;                        // NBUCK * BCAP  (19.2 MB)
        int2* ev    = part + (size_t)NBUCK * BCAP;        // E             (12.8 MB)
        int*  rpn   = (int*)(ev + E);                     // N+1
        int*  gcur  = rpn + (N + 1);                      // NBUCK
        int*  bbase = gcur + NBUCK;                       // NBUCK

        zero_small<<<(NBUCK + 255) / 256, blk, 0, stream>>>(gcur, NBUCK);
        part_k<<<(E + 4095) / 4096, blk, 0, stream>>>(srp, dsp, ew, gcur, part, E, NBUCK);
        scanB<<<1, 512, 0, stream>>>(gcur, bbase, rpn, N, NBUCK);
        csr_bucket<<<NBUCK, blk, 0, stream>>>(part, gcur, bbase, ev, rpn, dinv, N);

        // conv1 + conv2 (gather applies dinv scaling + self-loop + bias + relu)
        gemm_bf<128, 128, 0, 0><<<dim3(GR, 1), blk, 0, stream>>>(Xbf, w1t, nullptr, t2bf, 128, N, nullptr);
        gather_bf<<<GWB, blk, 0, stream>>>(rpn, ev, t2bf, dinv, b1, aggbf, N);
        gemm_bf<128, 128, 0, 0><<<dim3(GR, 1), blk, 0, stream>>>(aggbf, w2t, nullptr, t2bf, 128, N, nullptr);
        gather_bf<<<GWB, blk, 0, stream>>>(rpn, ev, t2bf, dinv, b2, aggbf, N);

        // fc2 head
        gemm_bf<128, 128, 1, 0><<<dim3(GR, 2), blk, 0, stream>>>(aggbf, fc2w1t, fc2_b1, t1bf, 256, N, nullptr);
        gemm_bf<256, 128, 1, 0><<<dim3(GR, 1), blk, 0, stream>>>(t1bf, fc2w2t, fc2_b2, t2bf, 128, N, nullptr);
        gemm_bf<128, 64, 1, 2><<<dim3(GR, 1), blk, 0, stream>>>(
            t2bf, fc2w3t, fc2_b3, out + (size_t)(1 + g) * N * 64, 64, N, Xs);
    }
}